// Round 2
// baseline (71344.867 us; speedup 1.0000x reference)
//
#include <hip/hip_runtime.h>
#include <math.h>

#define S_LEN 2048
#define FIN 9
#define NOUT 8
#define LBK 3
#define DD 11
#define K1 33
#define H2 512
#define UU 256
#define NSTEP 2044
#define MROW 4
#define LN_EPS 1e-3f

extern "C" __global__ void __launch_bounds__(256, 1)
solver(const float* __restrict__ inputs,
       const float* __restrict__ g1v, const float* __restrict__ b1v,
       const float* __restrict__ ew1, const float* __restrict__ eb1,
       const float* __restrict__ ew2, const float* __restrict__ eb2,
       const float* __restrict__ uw,  const float* __restrict__ ub,
       const float* __restrict__ g2v, const float* __restrict__ b2v,
       const float* __restrict__ bww,
       const float* __restrict__ dw1, const float* __restrict__ db1,
       const float* __restrict__ dw2, const float* __restrict__ db2,
       const int* __restrict__ fixv,
       float* __restrict__ out)
{
    __shared__ float x33[MROW][K1];        // LN1 output, reshaped (4 x 33)
    __shared__ float h1s[MROW][H2];        // tanh(enc1) (4 x 512)
    __shared__ float hs[MROW][UU];         // enc2 out (4 x 256)
    __shared__ float combs[MROW][UU + 1];  // st ++ ect (4 x 257)
    __shared__ float gs[MROW][H2];         // tanh(dec1) (4 x 512)
    __shared__ float win[MROW][LBK][NOUT]; // rolling window
    __shared__ float red[4][MROW * UU];    // k-split partials (4 x 1024)
    __shared__ float red2[8][32];          // stage-G partials
    __shared__ float wred[4][12];          // per-wave LN2/ect partials
    __shared__ float rowstat[MROW][3];     // mean, rstd, ect per row
    __shared__ float ynew[MROW][NOUT];

    const int tid = threadIdx.x;
    const int b0 = blockIdx.x * MROW;
    const int fx0 = fixv[0], fx1 = fixv[1];

    // init window = initial[:, 0:3, :] = inputs[:, 0:3, 1:9]
    if (tid < MROW * LBK * NOUT) {
        int r = tid / (LBK * NOUT);
        int rem = tid % (LBK * NOUT);
        int p = rem / NOUT, f = rem % NOUT;
        win[r][p][f] = inputs[((size_t)(b0 + r) * S_LEN + p) * FIN + 1 + f];
    }
    __syncthreads();

    for (int t = 0; t < NSTEP; ++t) {
        const int i = t + LBK;

        // ---- stage A: build x = LN1(concat(lc, win)), write x33 ----
        if (tid < MROW * LBK) {
            int r = tid / LBK, p = tid % LBK;
            int b = b0 + r;
            int tt = i - LBK + p;
            float ld = inputs[((size_t)b * S_LEN + tt) * FIN];
            float df = 0.0f;
            if (tt > 0) df = ld - inputs[((size_t)b * S_LEN + tt - 1) * FIN];
            float v[DD];
            v[0] = ld; v[1] = ld; v[2] = df;  // loading, integral(=loading), diff (0 at t=0)
            #pragma unroll
            for (int f = 0; f < NOUT; ++f) v[3 + f] = win[r][p][f];
            float m = 0.f;
            #pragma unroll
            for (int j = 0; j < DD; ++j) m += v[j];
            m *= (1.0f / DD);
            float var = 0.f;
            #pragma unroll
            for (int j = 0; j < DD; ++j) { float d = v[j] - m; var += d * d; }
            var *= (1.0f / DD);
            float rs = rsqrtf(var + LN_EPS);
            #pragma unroll
            for (int j = 0; j < DD; ++j)
                x33[r][p * DD + j] = (v[j] - m) * rs * g1v[j] + b1v[j];
        }
        __syncthreads();

        // ---- stage B: h1 = tanh(x @ ew1 + eb1)  (33 -> 512) ----
        {
            int c0 = tid * 2;
            float acc0[MROW], acc1[MROW];
            float bias0 = eb1[c0], bias1 = eb1[c0 + 1];
            #pragma unroll
            for (int r = 0; r < MROW; ++r) { acc0[r] = bias0; acc1[r] = bias1; }
            #pragma unroll 3
            for (int k = 0; k < K1; ++k) {
                float w0 = ew1[(size_t)k * H2 + c0];
                float w1_ = ew1[(size_t)k * H2 + c0 + 1];
                #pragma unroll
                for (int r = 0; r < MROW; ++r) {
                    float xv = x33[r][k];
                    acc0[r] += xv * w0;
                    acc1[r] += xv * w1_;
                }
            }
            #pragma unroll
            for (int r = 0; r < MROW; ++r) {
                h1s[r][c0]     = tanhf(acc0[r]);
                h1s[r][c0 + 1] = tanhf(acc1[r]);
            }
        }
        __syncthreads();

        // ---- stage C: h = h1 @ ew2 + eb2  (512 -> 256), k-split x4 ----
        {
            int cg = tid & 63, ks = tid >> 6;
            int c0 = cg * 4;
            float acc[4][MROW];
            #pragma unroll
            for (int j = 0; j < 4; ++j)
                #pragma unroll
                for (int r = 0; r < MROW; ++r) acc[j][r] = 0.f;
            int kbeg = ks * 128;
            #pragma unroll 4
            for (int k = kbeg; k < kbeg + 128; ++k) {
                const float4 wv = *reinterpret_cast<const float4*>(ew2 + (size_t)k * UU + c0);
                #pragma unroll
                for (int r = 0; r < MROW; ++r) {
                    float hv = h1s[r][k];
                    acc[0][r] += hv * wv.x;
                    acc[1][r] += hv * wv.y;
                    acc[2][r] += hv * wv.z;
                    acc[3][r] += hv * wv.w;
                }
            }
            #pragma unroll
            for (int r = 0; r < MROW; ++r)
                #pragma unroll
                for (int j = 0; j < 4; ++j)
                    red[ks][r * UU + c0 + j] = acc[j][r];
        }
        __syncthreads();
        {
            #pragma unroll
            for (int r = 0; r < MROW; ++r) {
                int o = r * UU + tid;
                hs[r][tid] = red[0][o] + red[1][o] + red[2][o] + red[3][o] + eb2[tid];
            }
        }
        __syncthreads();

        // ---- stage D: u = h @ uw + ub  (256 -> 256), k-split x4 ----
        {
            int cg = tid & 63, ks = tid >> 6;
            int c0 = cg * 4;
            float acc[4][MROW];
            #pragma unroll
            for (int j = 0; j < 4; ++j)
                #pragma unroll
                for (int r = 0; r < MROW; ++r) acc[j][r] = 0.f;
            int kbeg = ks * 64;
            #pragma unroll 4
            for (int k = kbeg; k < kbeg + 64; ++k) {
                const float4 wv = *reinterpret_cast<const float4*>(uw + (size_t)k * UU + c0);
                #pragma unroll
                for (int r = 0; r < MROW; ++r) {
                    float hv = hs[r][k];
                    acc[0][r] += hv * wv.x;
                    acc[1][r] += hv * wv.y;
                    acc[2][r] += hv * wv.z;
                    acc[3][r] += hv * wv.w;
                }
            }
            #pragma unroll
            for (int r = 0; r < MROW; ++r)
                #pragma unroll
                for (int j = 0; j < 4; ++j)
                    red[ks][r * UU + c0 + j] = acc[j][r];
        }
        __syncthreads();
        {
            #pragma unroll
            for (int r = 0; r < MROW; ++r) {
                int o = r * UU + tid;
                combs[r][tid] = red[0][o] + red[1][o] + red[2][o] + red[3][o] + ub[tid];
            }
        }
        __syncthreads();

        // ---- LN2 stats + ect = h @ beta_w : 12 sums via wave shuffle ----
        {
            float s[12];
            float bwc = bww[tid];
            #pragma unroll
            for (int r = 0; r < MROW; ++r) {
                float u = combs[r][tid];
                float hb = hs[r][tid] * bwc;
                s[r * 3 + 0] = u;
                s[r * 3 + 1] = u * u;
                s[r * 3 + 2] = hb;
            }
            #pragma unroll
            for (int mk = 1; mk < 64; mk <<= 1) {
                #pragma unroll
                for (int q = 0; q < 12; ++q) s[q] += __shfl_xor(s[q], mk);
            }
            int wv = tid >> 6, ln = tid & 63;
            if (ln == 0) {
                #pragma unroll
                for (int q = 0; q < 12; ++q) wred[wv][q] = s[q];
            }
        }
        __syncthreads();
        if (tid < MROW) {
            int r = tid;
            float t0 = wred[0][r*3+0] + wred[1][r*3+0] + wred[2][r*3+0] + wred[3][r*3+0];
            float t1 = wred[0][r*3+1] + wred[1][r*3+1] + wred[2][r*3+1] + wred[3][r*3+1];
            float t2 = wred[0][r*3+2] + wred[1][r*3+2] + wred[2][r*3+2] + wred[3][r*3+2];
            float mean = t0 * (1.0f / UU);
            float var  = t1 * (1.0f / UU) - mean * mean;
            rowstat[r][0] = mean;
            rowstat[r][1] = rsqrtf(var + LN_EPS);
            rowstat[r][2] = t2;
        }
        __syncthreads();
        {
            float g2c = g2v[tid], b2c = b2v[tid];
            #pragma unroll
            for (int r = 0; r < MROW; ++r) {
                float u = combs[r][tid];
                combs[r][tid] = (u - rowstat[r][0]) * rowstat[r][1] * g2c + b2c;
            }
            if (tid < MROW) combs[tid][UU] = rowstat[tid][2];
        }
        __syncthreads();

        // ---- stage F: g = tanh(comb @ dw1 + db1)  (257 -> 512) ----
        {
            int c0 = tid * 2;
            float acc0[MROW], acc1[MROW];
            float bias0 = db1[c0], bias1 = db1[c0 + 1];
            #pragma unroll
            for (int r = 0; r < MROW; ++r) { acc0[r] = bias0; acc1[r] = bias1; }
            #pragma unroll 4
            for (int k = 0; k < UU + 1; ++k) {
                float w0 = dw1[(size_t)k * H2 + c0];
                float w1_ = dw1[(size_t)k * H2 + c0 + 1];
                #pragma unroll
                for (int r = 0; r < MROW; ++r) {
                    float cv = combs[r][k];
                    acc0[r] += cv * w0;
                    acc1[r] += cv * w1_;
                }
            }
            #pragma unroll
            for (int r = 0; r < MROW; ++r) {
                gs[r][c0]     = tanhf(acc0[r]);
                gs[r][c0 + 1] = tanhf(acc1[r]);
            }
        }
        __syncthreads();

        // ---- stage G: y = g @ dw2 + db2  (512 -> 8), k-split x8 ----
        {
            int o = tid & 31, kc = tid >> 5;
            int r = o >> 3, f = o & 7;
            int kbeg = kc * 64;
            float p = 0.f;
            #pragma unroll 4
            for (int k = kbeg; k < kbeg + 64; ++k)
                p += gs[r][k] * dw2[(size_t)k * NOUT + f];
            red2[kc][o] = p;
        }
        __syncthreads();
        if (tid < 32) {
            int o = tid, r = o >> 3, f = o & 7;
            int b = b0 + r;
            float y = db2[f];
            #pragma unroll
            for (int kc = 0; kc < 8; ++kc) y += red2[kc][o];
            // y[:, fix] = initial[:, i+1, fix] = inputs[:, i+1, 1+fix]
            if (f == fx0) y = inputs[((size_t)b * S_LEN + i + 1) * FIN + 1 + fx0];
            if (f == fx1) y = inputs[((size_t)b * S_LEN + i + 1) * FIN + 1 + fx1];
            ynew[r][f] = y;
            out[((size_t)(f * 1024 + b)) * NSTEP + t] = y;
        }
        __syncthreads();

        // ---- window shift: win = [win[:,1:,:], y] ----
        {
            float wshift = 0.f;
            int sr = 0, sp = 0, sf = 0;
            bool doshift = tid < MROW * LBK * NOUT;
            if (doshift) {
                sr = tid / (LBK * NOUT);
                int rem = tid % (LBK * NOUT);
                sp = rem / NOUT; sf = rem % NOUT;
                wshift = (sp < LBK - 1) ? win[sr][sp + 1][sf] : ynew[sr][sf];
            }
            __syncthreads();
            if (doshift) win[sr][sp][sf] = wshift;
        }
        __syncthreads();
    }
}

extern "C" void kernel_launch(void* const* d_in, const int* in_sizes, int n_in,
                              void* d_out, int out_size, void* d_ws, size_t ws_size,
                              hipStream_t stream) {
    (void)in_sizes; (void)n_in; (void)d_ws; (void)ws_size; (void)out_size;
    dim3 grid(256), block(256);
    solver<<<grid, block, 0, stream>>>(
        (const float*)d_in[0],   // inputs
        (const float*)d_in[1],   // ln1_gamma
        (const float*)d_in[2],   // ln1_beta
        (const float*)d_in[3],   // enc_w1
        (const float*)d_in[4],   // enc_b1
        (const float*)d_in[5],   // enc_w2
        (const float*)d_in[6],   // enc_b2
        (const float*)d_in[7],   // upd_w
        (const float*)d_in[8],   // upd_b
        (const float*)d_in[9],   // ln2_gamma
        (const float*)d_in[10],  // ln2_beta
        (const float*)d_in[11],  // beta_w
        (const float*)d_in[12],  // dec_w1
        (const float*)d_in[13],  // dec_b1
        (const float*)d_in[14],  // dec_w2
        (const float*)d_in[15],  // dec_b2
        (const int*)d_in[16],    // fix
        (float*)d_out);
}

// Round 3
// 59274.237 us; speedup vs baseline: 1.2036x; 1.2036x over previous
//
#include <hip/hip_runtime.h>
#include <math.h>

#define S_LEN 2048
#define FIN 9
#define NOUT 8
#define LBK 3
#define DD 11
#define K1 33
#define H2 512
#define UU 256
#define NSTEP 2044
#define MROW 4
#define NT 1024
#define LN_EPS 1e-3f

// bf16 weight pool layout (element offsets)
#define N_EW1 (K1 * H2)          // 16896
#define N_EW2 (H2 * UU)          // 131072
#define N_UW  (UU * UU)          // 65536
#define N_DW1 ((UU + 1) * H2)    // 131584
#define N_DW2 (H2 * NOUT)        // 4096
#define O_EW1 0
#define O_EW2 (O_EW1 + N_EW1)    // 16896
#define O_UW  (O_EW2 + N_EW2)    // 147968
#define O_DW1 (O_UW + N_UW)      // 213504
#define O_DW2 (O_DW1 + N_DW1)    // 345088
#define W_TOT (O_DW2 + N_DW2)    // 349184

__device__ __forceinline__ unsigned short f2bf(float f) {
    unsigned u = __float_as_uint(f);
    u = (u + 0x7fffu + ((u >> 16) & 1u)) >> 16;   // RNE
    return (unsigned short)u;
}

template<bool BF16>
__device__ __forceinline__ float2 ldw2(const void* w, int idx) {
    if constexpr (BF16) {
        ushort2 u = *reinterpret_cast<const ushort2*>((const unsigned short*)w + idx);
        float2 f;
        f.x = __uint_as_float(((unsigned)u.x) << 16);
        f.y = __uint_as_float(((unsigned)u.y) << 16);
        return f;
    } else {
        return *reinterpret_cast<const float2*>((const float*)w + idx);
    }
}

template<bool BF16>
__device__ __forceinline__ float ldw1(const void* w, int idx) {
    if constexpr (BF16) {
        unsigned short u = ((const unsigned short*)w)[idx];
        return __uint_as_float(((unsigned)u) << 16);
    } else {
        return ((const float*)w)[idx];
    }
}

extern "C" __global__ void convw(const float* __restrict__ ew1, const float* __restrict__ ew2,
                                 const float* __restrict__ uw,  const float* __restrict__ dw1,
                                 const float* __restrict__ dw2, unsigned short* __restrict__ o)
{
    int i = blockIdx.x * blockDim.x + threadIdx.x;
    int stride = gridDim.x * blockDim.x;
    for (; i < W_TOT; i += stride) {
        float v;
        if (i < O_EW2)      v = ew1[i - O_EW1];
        else if (i < O_UW)  v = ew2[i - O_EW2];
        else if (i < O_DW1) v = uw[i - O_UW];
        else if (i < O_DW2) v = dw1[i - O_DW1];
        else                v = dw2[i - O_DW2];
        o[i] = f2bf(v);
    }
}

template<bool BF16>
__global__ __launch_bounds__(NT)
void solver(const float* __restrict__ inputs,
            const float* __restrict__ g1v, const float* __restrict__ b1v,
            const void* __restrict__ ew1, const float* __restrict__ eb1,
            const void* __restrict__ ew2, const float* __restrict__ eb2,
            const void* __restrict__ uw,  const float* __restrict__ ub,
            const float* __restrict__ g2v, const float* __restrict__ b2v,
            const float* __restrict__ bww,
            const void* __restrict__ dw1, const float* __restrict__ db1,
            const void* __restrict__ dw2, const float* __restrict__ db2,
            const int* __restrict__ fixv,
            float* __restrict__ out)
{
    __shared__ float x33[MROW][K1];
    __shared__ float h1s[MROW * H2];       // flat r*512+c
    __shared__ float hs[MROW * UU];        // flat r*256+c
    __shared__ float combs[MROW][UU + 1];
    __shared__ float gs[MROW * H2];        // flat r*512+c
    __shared__ float win[MROW][LBK][NOUT];
    __shared__ float redf[8192];           // k-split partials (32 KB)
    __shared__ float red2[32][32];
    __shared__ float wred[16][3];
    __shared__ float rowstat[MROW][3];
    __shared__ float ynew[MROW][NOUT];

    float2* redf2 = reinterpret_cast<float2*>(redf);

    const int tid = threadIdx.x;
    const int b0 = blockIdx.x * MROW;
    const int fx0 = fixv[0], fx1 = fixv[1];

    if (tid < MROW * LBK * NOUT) {
        int r = tid / (LBK * NOUT);
        int rem = tid % (LBK * NOUT);
        int p = rem / NOUT, f = rem % NOUT;
        win[r][p][f] = inputs[((size_t)(b0 + r) * S_LEN + p) * FIN + 1 + f];
    }
    __syncthreads();

    for (int t = 0; t < NSTEP; ++t) {
        const int i = t + LBK;

        // ---- stage A: x = LN1(concat(lc, win)) -> x33 ----
        if (tid < MROW * LBK) {
            int r = tid / LBK, p = tid % LBK;
            int b = b0 + r;
            int tt = i - LBK + p;
            float ld = inputs[((size_t)b * S_LEN + tt) * FIN];
            float df = 0.0f;
            if (tt > 0) df = ld - inputs[((size_t)b * S_LEN + tt - 1) * FIN];
            float v[DD];
            v[0] = ld; v[1] = ld; v[2] = df;
            #pragma unroll
            for (int f = 0; f < NOUT; ++f) v[3 + f] = win[r][p][f];
            float m = 0.f;
            #pragma unroll
            for (int j = 0; j < DD; ++j) m += v[j];
            m *= (1.0f / DD);
            float var = 0.f;
            #pragma unroll
            for (int j = 0; j < DD; ++j) { float d = v[j] - m; var += d * d; }
            var *= (1.0f / DD);
            float rs = rsqrtf(var + LN_EPS);
            #pragma unroll
            for (int j = 0; j < DD; ++j)
                x33[r][p * DD + j] = (v[j] - m) * rs * g1v[j] + b1v[j];
        }
        __syncthreads();

        // ---- stage B: h1 = tanh(x @ ew1 + eb1)  (33 -> 512), k-split x4 ----
        {
            int cc = tid & 255, c0 = cc * 2;
            int ks = tid >> 8;                   // 0..3
            int kbeg = ks * 8;
            int kend = (ks == 3) ? K1 : kbeg + 8;
            float2 acc[MROW];
            #pragma unroll
            for (int r = 0; r < MROW; ++r) acc[r] = make_float2(0.f, 0.f);
            for (int k = kbeg; k < kend; ++k) {
                float2 w = ldw2<BF16>(ew1, k * H2 + c0);
                #pragma unroll
                for (int r = 0; r < MROW; ++r) {
                    float xv = x33[r][k];
                    acc[r].x += xv * w.x;
                    acc[r].y += xv * w.y;
                }
            }
            #pragma unroll
            for (int r = 0; r < MROW; ++r)
                redf2[ks * 1024 + r * 256 + cc] = acc[r];
        }
        __syncthreads();
        {
            #pragma unroll
            for (int jj = 0; jj < 2; ++jj) {
                int o = tid + jj * 1024;
                float v = redf[o] + redf[2048 + o] + redf[4096 + o] + redf[6144 + o] + eb1[o & 511];
                h1s[o] = tanhf(v);
            }
        }
        __syncthreads();

        // ---- stage C: h = h1 @ ew2 + eb2  (512 -> 256), k-split x8 ----
        {
            int cc = tid & 127, c0 = cc * 2;
            int ks = tid >> 7;                   // 0..7
            int kbeg = ks * 64;
            float2 acc[MROW];
            #pragma unroll
            for (int r = 0; r < MROW; ++r) acc[r] = make_float2(0.f, 0.f);
            #pragma unroll 8
            for (int k = kbeg; k < kbeg + 64; ++k) {
                float2 w = ldw2<BF16>(ew2, k * UU + c0);
                #pragma unroll
                for (int r = 0; r < MROW; ++r) {
                    float hv = h1s[r * H2 + k];
                    acc[r].x += hv * w.x;
                    acc[r].y += hv * w.y;
                }
            }
            #pragma unroll
            for (int r = 0; r < MROW; ++r)
                redf2[ks * 512 + r * 128 + cc] = acc[r];
        }
        __syncthreads();
        {
            int o = tid;
            float v = eb2[o & 255];
            #pragma unroll
            for (int ks = 0; ks < 8; ++ks) v += redf[ks * 1024 + o];
            hs[o] = v;
        }
        __syncthreads();

        // ---- stage D: u = h @ uw + ub  (256 -> 256), k-split x8 ----
        {
            int cc = tid & 127, c0 = cc * 2;
            int ks = tid >> 7;                   // 0..7
            int kbeg = ks * 32;
            float2 acc[MROW];
            #pragma unroll
            for (int r = 0; r < MROW; ++r) acc[r] = make_float2(0.f, 0.f);
            #pragma unroll 8
            for (int k = kbeg; k < kbeg + 32; ++k) {
                float2 w = ldw2<BF16>(uw, k * UU + c0);
                #pragma unroll
                for (int r = 0; r < MROW; ++r) {
                    float hv = hs[r * UU + k];
                    acc[r].x += hv * w.x;
                    acc[r].y += hv * w.y;
                }
            }
            #pragma unroll
            for (int r = 0; r < MROW; ++r)
                redf2[ks * 512 + r * 128 + cc] = acc[r];
        }
        __syncthreads();
        {
            int o = tid, r = o >> 8, c = o & 255;
            float v = ub[c];
            #pragma unroll
            for (int ks = 0; ks < 8; ++ks) v += redf[ks * 1024 + o];
            combs[r][c] = v;
        }
        __syncthreads();

        // ---- LN2 stats + ect = h @ beta_w ----
        {
            int r = tid >> 8, c = tid & 255;
            float u = combs[r][c];
            float hb = hs[r * UU + c] * bww[c];
            float s0 = u, s1 = u * u, s2 = hb;
            #pragma unroll
            for (int mk = 1; mk < 64; mk <<= 1) {
                s0 += __shfl_xor(s0, mk);
                s1 += __shfl_xor(s1, mk);
                s2 += __shfl_xor(s2, mk);
            }
            if ((tid & 63) == 0) {
                int w = tid >> 6;
                wred[w][0] = s0; wred[w][1] = s1; wred[w][2] = s2;
            }
        }
        __syncthreads();
        if (tid < MROW) {
            int r = tid;
            float t0 = 0.f, t1 = 0.f, t2 = 0.f;
            #pragma unroll
            for (int w = 4 * r; w < 4 * r + 4; ++w) {
                t0 += wred[w][0]; t1 += wred[w][1]; t2 += wred[w][2];
            }
            float mean = t0 * (1.0f / UU);
            float var  = t1 * (1.0f / UU) - mean * mean;
            rowstat[r][0] = mean;
            rowstat[r][1] = rsqrtf(var + LN_EPS);
            rowstat[r][2] = t2;
        }
        __syncthreads();
        {
            int r = tid >> 8, c = tid & 255;
            float u = combs[r][c];
            combs[r][c] = (u - rowstat[r][0]) * rowstat[r][1] * g2v[c] + b2v[c];
            if (tid < MROW) combs[tid][UU] = rowstat[tid][2];
        }
        __syncthreads();

        // ---- stage F: g = tanh(comb @ dw1 + db1)  (257 -> 512), k-split x4 ----
        {
            int cc = tid & 255, c0 = cc * 2;
            int ks = tid >> 8;                   // 0..3
            int kbeg = ks * 64;
            int kend = (ks == 3) ? (UU + 1) : kbeg + 64;
            float2 acc[MROW];
            #pragma unroll
            for (int r = 0; r < MROW; ++r) acc[r] = make_float2(0.f, 0.f);
            #pragma unroll 8
            for (int k = kbeg; k < kend; ++k) {
                float2 w = ldw2<BF16>(dw1, k * H2 + c0);
                #pragma unroll
                for (int r = 0; r < MROW; ++r) {
                    float cv = combs[r][k];
                    acc[r].x += cv * w.x;
                    acc[r].y += cv * w.y;
                }
            }
            #pragma unroll
            for (int r = 0; r < MROW; ++r)
                redf2[ks * 1024 + r * 256 + cc] = acc[r];
        }
        __syncthreads();
        {
            #pragma unroll
            for (int jj = 0; jj < 2; ++jj) {
                int o = tid + jj * 1024;
                float v = redf[o] + redf[2048 + o] + redf[4096 + o] + redf[6144 + o] + db1[o & 511];
                gs[o] = tanhf(v);
            }
        }
        __syncthreads();

        // ---- stage G: y = g @ dw2 + db2  (512 -> 8), k-split x32 ----
        {
            int o = tid & 31, kc = tid >> 5;     // 0..31
            int r = o >> 3, f = o & 7;
            int kbeg = kc * 16;
            float p = 0.f;
            #pragma unroll 4
            for (int k = kbeg; k < kbeg + 16; ++k)
                p += gs[r * H2 + k] * ldw1<BF16>(dw2, k * NOUT + f);
            red2[kc][o] = p;
        }
        __syncthreads();
        if (tid < 32) {
            int o = tid, r = o >> 3, f = o & 7;
            int b = b0 + r;
            float y = db2[f];
            #pragma unroll
            for (int kc = 0; kc < 32; ++kc) y += red2[kc][o];
            if (f == fx0) y = inputs[((size_t)b * S_LEN + i + 1) * FIN + 1 + fx0];
            if (f == fx1) y = inputs[((size_t)b * S_LEN + i + 1) * FIN + 1 + fx1];
            ynew[r][f] = y;
            out[((size_t)(f * 1024 + b)) * NSTEP + t] = y;
        }
        __syncthreads();

        // ---- window shift ----
        {
            float wshift = 0.f;
            int sr = 0, sp = 0, sf = 0;
            bool doshift = tid < MROW * LBK * NOUT;
            if (doshift) {
                sr = tid / (LBK * NOUT);
                int rem = tid % (LBK * NOUT);
                sp = rem / NOUT; sf = rem % NOUT;
                wshift = (sp < LBK - 1) ? win[sr][sp + 1][sf] : ynew[sr][sf];
            }
            __syncthreads();
            if (doshift) win[sr][sp][sf] = wshift;
        }
        __syncthreads();
    }
}

extern "C" void kernel_launch(void* const* d_in, const int* in_sizes, int n_in,
                              void* d_out, int out_size, void* d_ws, size_t ws_size,
                              hipStream_t stream) {
    (void)in_sizes; (void)n_in; (void)out_size;
    const bool use_bf16 = (d_ws != nullptr) && (ws_size >= (size_t)W_TOT * sizeof(unsigned short));
    if (use_bf16) {
        unsigned short* wpool = (unsigned short*)d_ws;
        convw<<<256, 256, 0, stream>>>(
            (const float*)d_in[3], (const float*)d_in[5], (const float*)d_in[7],
            (const float*)d_in[12], (const float*)d_in[14], wpool);
        solver<true><<<256, NT, 0, stream>>>(
            (const float*)d_in[0],
            (const float*)d_in[1], (const float*)d_in[2],
            (const void*)(wpool + O_EW1), (const float*)d_in[4],
            (const void*)(wpool + O_EW2), (const float*)d_in[6],
            (const void*)(wpool + O_UW),  (const float*)d_in[8],
            (const float*)d_in[9], (const float*)d_in[10],
            (const float*)d_in[11],
            (const void*)(wpool + O_DW1), (const float*)d_in[13],
            (const void*)(wpool + O_DW2), (const float*)d_in[15],
            (const int*)d_in[16],
            (float*)d_out);
    } else {
        solver<false><<<256, NT, 0, stream>>>(
            (const float*)d_in[0],
            (const float*)d_in[1], (const float*)d_in[2],
            (const void*)d_in[3], (const float*)d_in[4],
            (const void*)d_in[5], (const float*)d_in[6],
            (const void*)d_in[7], (const float*)d_in[8],
            (const float*)d_in[9], (const float*)d_in[10],
            (const float*)d_in[11],
            (const void*)d_in[12], (const float*)d_in[13],
            (const void*)d_in[14], (const float*)d_in[15],
            (const int*)d_in[16],
            (float*)d_out);
    }
}

// Round 4
// 20862.415 us; speedup vs baseline: 3.4198x; 2.8412x over previous
//
#include <hip/hip_runtime.h>
#include <math.h>

#define S_LEN 2048
#define FIN 9
#define NOUT 8
#define LBK 3
#define DD 11
#define K1 33
#define H2 512
#define UU 256
#define NSTEP 2044
#define MR 16
#define LN_EPS 1e-3f

typedef __attribute__((ext_vector_type(8))) short short8;
typedef __attribute__((ext_vector_type(4))) float f32x4;
typedef __attribute__((ext_vector_type(4))) unsigned short us4;

// ---- packed B-fragment pool (bf16 elements) ----
// frag layout: for tile (nt,kt): 64 lanes x 8 bf16; elem = B[k][n],
// k = kt*32 + (lane>>4)*8 + j, n = nt*16 + (lane&15)
#define F_EW1 (32 * 2 * 512)
#define F_EW2 (16 * 16 * 512)
#define F_UW  (16 * 8 * 512)
#define F_DW1 (32 * 8 * 512)
#define F_DW2 (1 * 16 * 512)
#define O_EW1 0
#define O_EW2 (O_EW1 + F_EW1)
#define O_UW  (O_EW2 + F_EW2)
#define O_DW1 (O_UW + F_UW)
#define O_DW2 (O_DW1 + F_DW1)
#define W_TOT (O_DW2 + F_DW2)   // 368640 elems = 737280 B

__device__ __forceinline__ unsigned short f2bf(float f) {
    unsigned u = __float_as_uint(f);
    u = (u + 0x7fffu + ((u >> 16) & 1u)) >> 16;
    return (unsigned short)u;
}
__device__ __forceinline__ float bf2f(unsigned short u) {
    return __uint_as_float(((unsigned)u) << 16);
}
__device__ __forceinline__ float ftanh(float x) {
    float ax = fabsf(x);
    float e = __expf(-2.0f * ax);
    float r = __fdividef(1.0f - e, 1.0f + e);
    return copysignf(r, x);
}

extern "C" __global__ void convw(const float* __restrict__ ew1, const float* __restrict__ ew2,
                                 const float* __restrict__ uw,  const float* __restrict__ dw1,
                                 const float* __restrict__ dw2, unsigned short* __restrict__ o)
{
    int i = blockIdx.x * blockDim.x + threadIdx.x;
    if (i >= W_TOT) return;
    int p, KT, K, N; const float* W;
    if (i < O_EW2)      { p = i - O_EW1; KT = 2;  K = 33;  N = 512; W = ew1; }
    else if (i < O_UW)  { p = i - O_EW2; KT = 16; K = 512; N = 256; W = ew2; }
    else if (i < O_DW1) { p = i - O_UW;  KT = 8;  K = 256; N = 256; W = uw;  }
    else if (i < O_DW2) { p = i - O_DW1; KT = 8;  K = 256; N = 512; W = dw1; }
    else                { p = i - O_DW2; KT = 16; K = 512; N = 8;   W = dw2; }
    int frag = p >> 9, rem = p & 511;
    int ln = rem >> 3, j = rem & 7;
    int nt = frag / KT, kt = frag % KT;
    int k = kt * 32 + (ln >> 4) * 8 + j;
    int n = nt * 16 + (ln & 15);
    float v = 0.f;
    if (k < K && n < N) v = W[k * N + n];
    o[i] = f2bf(v);
}

extern "C" __global__ void __launch_bounds__(1024)
solver(const float* __restrict__ inputs,
       const unsigned short* __restrict__ pool,
       const float* __restrict__ g1v, const float* __restrict__ b1v,
       const float* __restrict__ eb1, const float* __restrict__ eb2,
       const float* __restrict__ ub,  const float* __restrict__ g2v,
       const float* __restrict__ b2v, const float* __restrict__ bww,
       const float* __restrict__ dw1, const float* __restrict__ db1,
       const float* __restrict__ db2, const int* __restrict__ fixv,
       float* __restrict__ out)
{
    // activations: 16 rows, padded strides == 4 dw mod 32 for bank spread
    __shared__ unsigned short xs[MR * 72];    // LN1 out, K padded to 64 (zeros)
    __shared__ unsigned short h1[MR * 520];   // tanh(enc1), 512 cols
    __shared__ unsigned short hsb[MR * 264];  // enc2 out, 256 cols
    __shared__ float          uu[MR * 260];   // upd out fp32 (pre-LN2)
    __shared__ unsigned short cmb[MR * 264];  // LN2 out bf16, 256 cols
    __shared__ unsigned short gsb[MR * 520];  // tanh(dec1), 512 cols
    __shared__ float red2[4][MR][17];
    __shared__ float ects[MR], rs0[MR], rs1[MR];
    __shared__ float ring[3][MR][NOUT];
    __shared__ float s_eb1[512], s_eb2[256], s_ub[256], s_db1[512], s_db2[8];
    __shared__ float s_bw[256], s_g2[256], s_b2[256], s_w257[512];
    __shared__ float s_g1[DD], s_b1[DD];

    const int tid = threadIdx.x;
    const int lane = tid & 63;
    const int wv = tid >> 6;      // wave 0..15
    const int q = lane >> 4;      // quad 0..3
    const int lc = lane & 15;     // tile col / A-row
    const int b0 = blockIdx.x * MR;
    const int fx0 = fixv[0], fx1 = fixv[1];

    // ---- preload params to LDS; zero xs ----
    for (int z = tid; z < MR * 72; z += 1024) xs[z] = 0;
    for (int z = tid; z < 512; z += 1024) { s_eb1[z] = eb1[z]; s_db1[z] = db1[z]; s_w257[z] = dw1[256 * 512 + z]; }
    for (int z = tid; z < 256; z += 1024) { s_eb2[z] = eb2[z]; s_ub[z] = ub[z]; s_bw[z] = bww[z]; s_g2[z] = g2v[z]; s_b2[z] = b2v[z]; }
    if (tid < 8) s_db2[tid] = db2[tid];
    if (tid >= 16 && tid < 16 + DD) { s_g1[tid - 16] = g1v[tid - 16]; s_b1[tid - 16] = b1v[tid - 16]; }
    if (tid < MR * LBK * NOUT) {
        int r = tid / (LBK * NOUT);
        int rem = tid % (LBK * NOUT);
        int p = rem / NOUT, f = rem % NOUT;
        ring[p][r][f] = inputs[((size_t)(b0 + r) * S_LEN + p) * FIN + 1 + f];
    }
    __syncthreads();

    for (int t = 0; t < NSTEP; ++t) {
        // ---- stage A: LN1 over [lc, win] -> xs (bf16) ----
        if (tid < MR * LBK) {
            int r = tid / LBK, p = tid % LBK;
            int b = b0 + r;
            int tt = t + p;
            float ld = inputs[((size_t)b * S_LEN + tt) * FIN];
            float df = (tt > 0) ? ld - inputs[((size_t)b * S_LEN + tt - 1) * FIN] : 0.f;
            float v[DD];
            v[0] = ld; v[1] = ld; v[2] = df;
            #pragma unroll
            for (int f = 0; f < NOUT; ++f) v[3 + f] = ring[(tt) % 3][r][f];
            float m = 0.f;
            #pragma unroll
            for (int j = 0; j < DD; ++j) m += v[j];
            m *= (1.0f / DD);
            float var = 0.f;
            #pragma unroll
            for (int j = 0; j < DD; ++j) { float d = v[j] - m; var += d * d; }
            var *= (1.0f / DD);
            float rs = rsqrtf(var + LN_EPS);
            #pragma unroll
            for (int j = 0; j < DD; ++j)
                xs[r * 72 + p * DD + j] = f2bf((v[j] - m) * rs * s_g1[j] + s_b1[j]);
        }
        __syncthreads();

        // ---- stage B: h1 = tanh(x @ ew1 + eb1), 33(pad64)->512, MFMA ----
        {
            #pragma unroll
            for (int half = 0; half < 2; ++half) {
                int nt = wv * 2 + half;
                float bias = s_eb1[nt * 16 + lc];
                f32x4 acc = {bias, bias, bias, bias};
                #pragma unroll
                for (int kt = 0; kt < 2; ++kt) {
                    short8 af = *(const short8*)&xs[lc * 72 + kt * 32 + q * 8];
                    short8 bf = *(const short8*)&pool[O_EW1 + ((nt * 2 + kt) << 9) + (lane << 3)];
                    acc = __builtin_amdgcn_mfma_f32_16x16x32_bf16(af, bf, acc, 0, 0, 0);
                }
                int col = nt * 16 + lc;
                #pragma unroll
                for (int r = 0; r < 4; ++r)
                    h1[(q * 4 + r) * 520 + col] = f2bf(ftanh(acc[r]));
            }
        }
        __syncthreads();

        // ---- stage C: h = h1 @ ew2 + eb2, 512->256, MFMA ----
        {
            int nt = wv;
            float bias = s_eb2[nt * 16 + lc];
            f32x4 acc = {bias, bias, bias, bias};
            #pragma unroll 4
            for (int kt = 0; kt < 16; ++kt) {
                short8 af = *(const short8*)&h1[lc * 520 + kt * 32 + q * 8];
                short8 bf = *(const short8*)&pool[O_EW2 + ((nt * 16 + kt) << 9) + (lane << 3)];
                acc = __builtin_amdgcn_mfma_f32_16x16x32_bf16(af, bf, acc, 0, 0, 0);
            }
            int col = nt * 16 + lc;
            #pragma unroll
            for (int r = 0; r < 4; ++r)
                hsb[(q * 4 + r) * 264 + col] = f2bf(acc[r]);
        }
        __syncthreads();

        // ---- stage D: u = h @ uw + ub, 256->256, MFMA -> uu fp32 ----
        {
            int nt = wv;
            float bias = s_ub[nt * 16 + lc];
            f32x4 acc = {bias, bias, bias, bias};
            #pragma unroll 4
            for (int kt = 0; kt < 8; ++kt) {
                short8 af = *(const short8*)&hsb[lc * 264 + kt * 32 + q * 8];
                short8 bf = *(const short8*)&pool[O_UW + ((nt * 8 + kt) << 9) + (lane << 3)];
                acc = __builtin_amdgcn_mfma_f32_16x16x32_bf16(af, bf, acc, 0, 0, 0);
            }
            int col = nt * 16 + lc;
            #pragma unroll
            for (int r = 0; r < 4; ++r)
                uu[(q * 4 + r) * 260 + col] = acc[r];
        }
        __syncthreads();

        // ---- LN2 stats + ect: wave wv handles row wv ----
        {
            float4 u4 = *(const float4*)&uu[wv * 260 + lane * 4];
            us4 h4 = *(const us4*)&hsb[wv * 264 + lane * 4];
            float4 b4 = *(const float4*)&s_bw[lane * 4];
            float s0 = u4.x + u4.y + u4.z + u4.w;
            float s1 = u4.x * u4.x + u4.y * u4.y + u4.z * u4.z + u4.w * u4.w;
            float s2 = bf2f(h4[0]) * b4.x + bf2f(h4[1]) * b4.y + bf2f(h4[2]) * b4.z + bf2f(h4[3]) * b4.w;
            #pragma unroll
            for (int mk = 1; mk < 64; mk <<= 1) {
                s0 += __shfl_xor(s0, mk);
                s1 += __shfl_xor(s1, mk);
                s2 += __shfl_xor(s2, mk);
            }
            if (lane == 0) {
                float mean = s0 * (1.0f / UU);
                float var = s1 * (1.0f / UU) - mean * mean;
                rs0[wv] = mean;
                rs1[wv] = rsqrtf(var + LN_EPS);
                ects[wv] = s2;
            }
        }
        __syncthreads();

        // ---- comb = LN2(u)*g2+b2 -> cmb bf16 ----
        {
            int r = wv;
            float4 u4 = *(const float4*)&uu[r * 260 + lane * 4];
            float4 g4 = *(const float4*)&s_g2[lane * 4];
            float4 b4 = *(const float4*)&s_b2[lane * 4];
            float m = rs0[r], rstd = rs1[r];
            us4 o;
            o[0] = f2bf((u4.x - m) * rstd * g4.x + b4.x);
            o[1] = f2bf((u4.y - m) * rstd * g4.y + b4.y);
            o[2] = f2bf((u4.z - m) * rstd * g4.z + b4.z);
            o[3] = f2bf((u4.w - m) * rstd * g4.w + b4.w);
            *(us4*)&cmb[r * 264 + lane * 4] = o;
        }
        __syncthreads();

        // ---- stage F: g = tanh(comb @ dw1[0:256] + ect*w257 + db1), MFMA + rank-1 ----
        {
            #pragma unroll
            for (int half = 0; half < 2; ++half) {
                int nt = wv * 2 + half;
                float bias = s_db1[nt * 16 + lc];
                f32x4 acc = {bias, bias, bias, bias};
                #pragma unroll 4
                for (int kt = 0; kt < 8; ++kt) {
                    short8 af = *(const short8*)&cmb[lc * 264 + kt * 32 + q * 8];
                    short8 bf = *(const short8*)&pool[O_DW1 + ((nt * 8 + kt) << 9) + (lane << 3)];
                    acc = __builtin_amdgcn_mfma_f32_16x16x32_bf16(af, bf, acc, 0, 0, 0);
                }
                int col = nt * 16 + lc;
                float wc = s_w257[col];
                #pragma unroll
                for (int r = 0; r < 4; ++r) {
                    int row = q * 4 + r;
                    gsb[row * 520 + col] = f2bf(ftanh(acc[r] + ects[row] * wc));
                }
            }
        }
        __syncthreads();

        // ---- stage G: y = g @ dw2, 512->8(pad16), MFMA on waves 0..3 ----
        if (wv < 4) {
            f32x4 acc = {0.f, 0.f, 0.f, 0.f};
            #pragma unroll
            for (int kk = 0; kk < 4; ++kk) {
                int kt = wv * 4 + kk;
                short8 af = *(const short8*)&gsb[lc * 520 + kt * 32 + q * 8];
                short8 bf = *(const short8*)&pool[O_DW2 + (kt << 9) + (lane << 3)];
                acc = __builtin_amdgcn_mfma_f32_16x16x32_bf16(af, bf, acc, 0, 0, 0);
            }
            #pragma unroll
            for (int r = 0; r < 4; ++r)
                red2[wv][q * 4 + r][lc] = acc[r];
        }
        __syncthreads();

        // ---- finalize: bias, fix override, out store, ring update ----
        if (tid < 128) {
            int r = tid >> 3, f = tid & 7;
            int b = b0 + r;
            float y = s_db2[f] + red2[0][r][f] + red2[1][r][f] + red2[2][r][f] + red2[3][r][f];
            if (f == fx0) y = inputs[((size_t)b * S_LEN + t + 4) * FIN + 1 + fx0];
            if (f == fx1) y = inputs[((size_t)b * S_LEN + t + 4) * FIN + 1 + fx1];
            out[((size_t)(f * 1024 + b)) * NSTEP + t] = y;
            ring[t % 3][r][f] = y;
        }
        __syncthreads();
    }
}

// ================= fallback (fp32 VALU, R3-proven) =================
#define MROW 4
#define NTF 1024
__global__ __launch_bounds__(NTF)
void solver_fb(const float* __restrict__ inputs,
               const float* __restrict__ g1v, const float* __restrict__ b1v,
               const float* __restrict__ ew1, const float* __restrict__ eb1,
               const float* __restrict__ ew2, const float* __restrict__ eb2,
               const float* __restrict__ uw,  const float* __restrict__ ub,
               const float* __restrict__ g2v, const float* __restrict__ b2v,
               const float* __restrict__ bww,
               const float* __restrict__ dw1, const float* __restrict__ db1,
               const float* __restrict__ dw2, const float* __restrict__ db2,
               const int* __restrict__ fixv,
               float* __restrict__ out)
{
    __shared__ float x33[MROW][K1];
    __shared__ float h1s[MROW * H2];
    __shared__ float hs[MROW * UU];
    __shared__ float combs[MROW][UU + 1];
    __shared__ float gs[MROW * H2];
    __shared__ float win[MROW][LBK][NOUT];
    __shared__ float redf[8192];
    __shared__ float red2[32][32];
    __shared__ float wred[16][3];
    __shared__ float rowstat[MROW][3];
    __shared__ float ynew[MROW][NOUT];
    float2* redf2 = reinterpret_cast<float2*>(redf);
    const int tid = threadIdx.x;
    const int b0 = blockIdx.x * MROW;
    const int fx0 = fixv[0], fx1 = fixv[1];
    if (tid < MROW * LBK * NOUT) {
        int r = tid / (LBK * NOUT);
        int rem = tid % (LBK * NOUT);
        int p = rem / NOUT, f = rem % NOUT;
        win[r][p][f] = inputs[((size_t)(b0 + r) * S_LEN + p) * FIN + 1 + f];
    }
    __syncthreads();
    for (int t = 0; t < NSTEP; ++t) {
        const int i = t + LBK;
        if (tid < MROW * LBK) {
            int r = tid / LBK, p = tid % LBK;
            int b = b0 + r;
            int tt = i - LBK + p;
            float ld = inputs[((size_t)b * S_LEN + tt) * FIN];
            float df = (tt > 0) ? ld - inputs[((size_t)b * S_LEN + tt - 1) * FIN] : 0.f;
            float v[DD];
            v[0] = ld; v[1] = ld; v[2] = df;
            #pragma unroll
            for (int f = 0; f < NOUT; ++f) v[3 + f] = win[r][p][f];
            float m = 0.f;
            #pragma unroll
            for (int j = 0; j < DD; ++j) m += v[j];
            m *= (1.0f / DD);
            float var = 0.f;
            #pragma unroll
            for (int j = 0; j < DD; ++j) { float d = v[j] - m; var += d * d; }
            var *= (1.0f / DD);
            float rs = rsqrtf(var + LN_EPS);
            #pragma unroll
            for (int j = 0; j < DD; ++j)
                x33[r][p * DD + j] = (v[j] - m) * rs * g1v[j] + b1v[j];
        }
        __syncthreads();
        {
            int cc = tid & 255, c0 = cc * 2;
            int ks = tid >> 8;
            int kbeg = ks * 8;
            int kend = (ks == 3) ? K1 : kbeg + 8;
            float2 acc[MROW];
            #pragma unroll
            for (int r = 0; r < MROW; ++r) acc[r] = make_float2(0.f, 0.f);
            for (int k = kbeg; k < kend; ++k) {
                float2 w = *reinterpret_cast<const float2*>(ew1 + (size_t)k * H2 + c0);
                #pragma unroll
                for (int r = 0; r < MROW; ++r) {
                    float xv = x33[r][k];
                    acc[r].x += xv * w.x; acc[r].y += xv * w.y;
                }
            }
            #pragma unroll
            for (int r = 0; r < MROW; ++r) redf2[ks * 1024 + r * 256 + cc] = acc[r];
        }
        __syncthreads();
        {
            #pragma unroll
            for (int jj = 0; jj < 2; ++jj) {
                int o = tid + jj * 1024;
                float v = redf[o] + redf[2048 + o] + redf[4096 + o] + redf[6144 + o] + eb1[o & 511];
                h1s[o] = tanhf(v);
            }
        }
        __syncthreads();
        {
            int cc = tid & 127, c0 = cc * 2;
            int ks = tid >> 7;
            int kbeg = ks * 64;
            float2 acc[MROW];
            #pragma unroll
            for (int r = 0; r < MROW; ++r) acc[r] = make_float2(0.f, 0.f);
            #pragma unroll 8
            for (int k = kbeg; k < kbeg + 64; ++k) {
                float2 w = *reinterpret_cast<const float2*>(ew2 + (size_t)k * UU + c0);
                #pragma unroll
                for (int r = 0; r < MROW; ++r) {
                    float hv = h1s[r * H2 + k];
                    acc[r].x += hv * w.x; acc[r].y += hv * w.y;
                }
            }
            #pragma unroll
            for (int r = 0; r < MROW; ++r) redf2[ks * 512 + r * 128 + cc] = acc[r];
        }
        __syncthreads();
        {
            int o = tid;
            float v = eb2[o & 255];
            #pragma unroll
            for (int ks = 0; ks < 8; ++ks) v += redf[ks * 1024 + o];
            hs[o] = v;
        }
        __syncthreads();
        {
            int cc = tid & 127, c0 = cc * 2;
            int ks = tid >> 7;
            int kbeg = ks * 32;
            float2 acc[MROW];
            #pragma unroll
            for (int r = 0; r < MROW; ++r) acc[r] = make_float2(0.f, 0.f);
            #pragma unroll 8
            for (int k = kbeg; k < kbeg + 32; ++k) {
                float2 w = *reinterpret_cast<const float2*>(uw + (size_t)k * UU + c0);
                #pragma unroll
                for (int r = 0; r < MROW; ++r) {
                    float hv = hs[r * UU + k];
                    acc[r].x += hv * w.x; acc[r].y += hv * w.y;
                }
            }
            #pragma unroll
            for (int r = 0; r < MROW; ++r) redf2[ks * 512 + r * 128 + cc] = acc[r];
        }
        __syncthreads();
        {
            int o = tid, r = o >> 8, c = o & 255;
            float v = ub[c];
            #pragma unroll
            for (int ks = 0; ks < 8; ++ks) v += redf[ks * 1024 + o];
            combs[r][c] = v;
        }
        __syncthreads();
        {
            int r = tid >> 8, c = tid & 255;
            float u = combs[r][c];
            float hb = hs[r * UU + c] * bww[c];
            float s0 = u, s1 = u * u, s2 = hb;
            #pragma unroll
            for (int mk = 1; mk < 64; mk <<= 1) {
                s0 += __shfl_xor(s0, mk);
                s1 += __shfl_xor(s1, mk);
                s2 += __shfl_xor(s2, mk);
            }
            if ((tid & 63) == 0) {
                int w = tid >> 6;
                wred[w][0] = s0; wred[w][1] = s1; wred[w][2] = s2;
            }
        }
        __syncthreads();
        if (tid < MROW) {
            int r = tid;
            float t0 = 0.f, t1 = 0.f, t2 = 0.f;
            #pragma unroll
            for (int w = 4 * r; w < 4 * r + 4; ++w) { t0 += wred[w][0]; t1 += wred[w][1]; t2 += wred[w][2]; }
            float mean = t0 * (1.0f / UU);
            float var = t1 * (1.0f / UU) - mean * mean;
            rowstat[r][0] = mean; rowstat[r][1] = rsqrtf(var + LN_EPS); rowstat[r][2] = t2;
        }
        __syncthreads();
        {
            int r = tid >> 8, c = tid & 255;
            float u = combs[r][c];
            combs[r][c] = (u - rowstat[r][0]) * rowstat[r][1] * g2v[c] + b2v[c];
            if (tid < MROW) combs[tid][UU] = rowstat[tid][2];
        }
        __syncthreads();
        {
            int cc = tid & 255, c0 = cc * 2;
            int ks = tid >> 8;
            int kbeg = ks * 64;
            int kend = (ks == 3) ? (UU + 1) : kbeg + 64;
            float2 acc[MROW];
            #pragma unroll
            for (int r = 0; r < MROW; ++r) acc[r] = make_float2(0.f, 0.f);
            #pragma unroll 8
            for (int k = kbeg; k < kend; ++k) {
                float2 w = *reinterpret_cast<const float2*>(dw1 + (size_t)k * H2 + c0);
                #pragma unroll
                for (int r = 0; r < MROW; ++r) {
                    float cv = combs[r][k];
                    acc[r].x += cv * w.x; acc[r].y += cv * w.y;
                }
            }
            #pragma unroll
            for (int r = 0; r < MROW; ++r) redf2[ks * 1024 + r * 256 + cc] = acc[r];
        }
        __syncthreads();
        {
            #pragma unroll
            for (int jj = 0; jj < 2; ++jj) {
                int o = tid + jj * 1024;
                float v = redf[o] + redf[2048 + o] + redf[4096 + o] + redf[6144 + o] + db1[o & 511];
                gs[o] = tanhf(v);
            }
        }
        __syncthreads();
        {
            int o = tid & 31, kc = tid >> 5;
            int r = o >> 3, f = o & 7;
            int kbeg = kc * 16;
            float p = 0.f;
            #pragma unroll 4
            for (int k = kbeg; k < kbeg + 16; ++k)
                p += gs[r * H2 + k] * dw2[(size_t)k * NOUT + f];
            red2[kc][o] = p;
        }
        __syncthreads();
        if (tid < 32) {
            int o = tid, r = o >> 3, f = o & 7;
            int b = b0 + r;
            float y = db2[f];
            #pragma unroll
            for (int kc = 0; kc < 32; ++kc) y += red2[kc][o];
            if (f == fx0) y = inputs[((size_t)b * S_LEN + i + 1) * FIN + 1 + fx0];
            if (f == fx1) y = inputs[((size_t)b * S_LEN + i + 1) * FIN + 1 + fx1];
            ynew[r][f] = y;
            out[((size_t)(f * 1024 + b)) * NSTEP + t] = y;
        }
        __syncthreads();
        {
            float wshift = 0.f;
            int sr = 0, sp = 0, sf = 0;
            bool doshift = tid < MROW * LBK * NOUT;
            if (doshift) {
                sr = tid / (LBK * NOUT);
                int rem = tid % (LBK * NOUT);
                sp = rem / NOUT; sf = rem % NOUT;
                wshift = (sp < LBK - 1) ? win[sr][sp + 1][sf] : ynew[sr][sf];
            }
            __syncthreads();
            if (doshift) win[sr][sp][sf] = wshift;
        }
        __syncthreads();
    }
}

extern "C" void kernel_launch(void* const* d_in, const int* in_sizes, int n_in,
                              void* d_out, int out_size, void* d_ws, size_t ws_size,
                              hipStream_t stream) {
    (void)in_sizes; (void)n_in; (void)out_size;
    const bool use_mfma = (d_ws != nullptr) && (ws_size >= (size_t)W_TOT * sizeof(unsigned short));
    if (use_mfma) {
        unsigned short* pool = (unsigned short*)d_ws;
        convw<<<(W_TOT + 255) / 256, 256, 0, stream>>>(
            (const float*)d_in[3], (const float*)d_in[5], (const float*)d_in[7],
            (const float*)d_in[12], (const float*)d_in[14], pool);
        solver<<<64, 1024, 0, stream>>>(
            (const float*)d_in[0], pool,
            (const float*)d_in[1], (const float*)d_in[2],
            (const float*)d_in[4], (const float*)d_in[6],
            (const float*)d_in[8], (const float*)d_in[9],
            (const float*)d_in[10], (const float*)d_in[11],
            (const float*)d_in[12], (const float*)d_in[13],
            (const float*)d_in[15], (const int*)d_in[16],
            (float*)d_out);
    } else {
        solver_fb<<<256, NTF, 0, stream>>>(
            (const float*)d_in[0],
            (const float*)d_in[1], (const float*)d_in[2],
            (const float*)d_in[3], (const float*)d_in[4],
            (const float*)d_in[5], (const float*)d_in[6],
            (const float*)d_in[7], (const float*)d_in[8],
            (const float*)d_in[9], (const float*)d_in[10],
            (const float*)d_in[11],
            (const float*)d_in[12], (const float*)d_in[13],
            (const float*)d_in[14], (const float*)d_in[15],
            (const int*)d_in[16],
            (float*)d_out);
    }
}